// Round 15
// baseline (293.405 us; speedup 1.0000x reference)
//
#include <hip/hip_runtime.h>
#include <math.h>

#define CIN 256
#define CB 64
#define COUT 256
#define KNB 27
#define EPS 1e-5f

typedef unsigned short u16;
typedef __attribute__((ext_vector_type(8))) short short8;
typedef __attribute__((ext_vector_type(4))) float f32x4;

typedef const __attribute__((address_space(1))) unsigned int* gas_u32p;
typedef __attribute__((address_space(3))) unsigned int* las_u32p;
#define GLL(g, p) __builtin_amdgcn_global_load_lds((gas_u32p)(const void*)(g), \
        (las_u32p)(void*)(p), 16, 0, 0)

__device__ inline short f2bf(float f) {
    union { float f; unsigned u; } v; v.f = f;
    unsigned r = v.u + 0x7fff + ((v.u >> 16) & 1);   // RNE
    return (short)(r >> 16);
}
__device__ inline float bf2f(short s) {
    union { unsigned u; float f; } v; v.u = ((unsigned)(u16)s) << 16;
    return v.f;
}
__device__ inline short8 pack8(float4 x0, float4 x1) {
    short8 r;
    r[0] = f2bf(x0.x); r[1] = f2bf(x0.y); r[2] = f2bf(x0.z); r[3] = f2bf(x0.w);
    r[4] = f2bf(x1.x); r[5] = f2bf(x1.y); r[6] = f2bf(x1.z); r[7] = f2bf(x1.w);
    return r;
}

// ---------------------------------------------------------------------------
// Weight prep: bf16 conversion + transposes (+ XOR-swizzled w3 LDS image)
// ---------------------------------------------------------------------------
__global__ void k_prep(const float* __restrict__ w1a, const float* __restrict__ w3,
                       const float* __restrict__ w1b, u16* __restrict__ w1at,
                       u16* __restrict__ w3img, u16* __restrict__ w1bt)
{
    int i = blockIdx.x * 256 + threadIdx.x;
    if (i < 16384) {
        int k = i >> 6, d = i & 63;
        w1at[d * 256 + k] = (u16)f2bf(w1a[i]);
    } else if (i < 126976) {
        int j = i - 16384;
        int k = j >> 12, c = (j >> 6) & 63, d = j & 63;
        w3img[(size_t)k * 4096 + d * 64 + (c ^ ((d & 7) << 3))] = (u16)f2bf(w3[j]);
    } else if (i < 143360) {
        int j = i - 126976;
        int c = j >> 8, d = j & 255;
        w1bt[d * 64 + c] = (u16)f2bf(w1b[j]);
    }
}

// ---------------------------------------------------------------------------
// GEMM1: t1[N,64](bf16, RAW) = data[N,256](f32->bf16) @ w1a ; GN1 stats
// ---------------------------------------------------------------------------
__global__ __launch_bounds__(256) void k_gemm1(const float* __restrict__ data,
        const u16* __restrict__ w1at, u16* __restrict__ t1,
        float* __restrict__ stats, int n)
{
    __shared__ float s_sum[32], s_sq[32];
    const int tid = threadIdx.x;
    if (tid < 32) { s_sum[tid] = 0.f; s_sq[tid] = 0.f; }
    __syncthreads();
    const int l = tid & 63, wv = tid >> 6;
    const int ll = l & 15, lh = l >> 4;
    const int rowbase = blockIdx.x * 256 + wv * 64;

    f32x4 acc[4][4] = {};
#pragma unroll
    for (int kc = 0; kc < 8; ++kc) {
        short8 b[4];
#pragma unroll
        for (int f = 0; f < 4; ++f)
            b[f] = *(const short8*)(w1at + (size_t)(f * 16 + ll) * 256 + kc * 32 + lh * 8);
#pragma unroll
        for (int rt = 0; rt < 4; ++rt) {
            int row = rowbase + rt * 16 + ll;
            int rowc = (row < n) ? row : 0;
            const float* ar = data + (size_t)rowc * CIN + kc * 32 + lh * 8;
            short8 a = pack8(*(const float4*)ar, *(const float4*)(ar + 4));
#pragma unroll
            for (int f = 0; f < 4; ++f)
                acc[rt][f] = __builtin_amdgcn_mfma_f32_16x16x32_bf16(a, b[f], acc[rt][f], 0, 0, 0);
        }
    }
    float gs[4] = {0.f, 0.f, 0.f, 0.f}, gq[4] = {0.f, 0.f, 0.f, 0.f};
#pragma unroll
    for (int rt = 0; rt < 4; ++rt) {
#pragma unroll
        for (int f = 0; f < 4; ++f) {
#pragma unroll
            for (int r = 0; r < 4; ++r) {
                int rr = rowbase + rt * 16 + lh * 4 + r;
                if (rr < n) {
                    float v = acc[rt][f][r];
                    t1[(size_t)rr * CB + f * 16 + ll] = (u16)f2bf(v);
                    gs[f] += v; gq[f] += v * v;
                }
            }
        }
    }
#pragma unroll
    for (int f = 0; f < 4; ++f) {
        float s = gs[f], q = gq[f];
        s += __shfl_xor(s, 1); s += __shfl_xor(s, 16); s += __shfl_xor(s, 32);
        q += __shfl_xor(q, 1); q += __shfl_xor(q, 16); q += __shfl_xor(q, 32);
        if ((l & 0x31) == 0) {
            atomicAdd(&s_sum[f * 8 + (ll >> 1)], s);
            atomicAdd(&s_sq [f * 8 + (ll >> 1)], q);
        }
    }
    __syncthreads();
    if (tid < 32) {
        atomicAdd(&stats[tid], s_sum[tid]);
        atomicAdd(&stats[32 + tid], s_sq[tid]);
    }
}

// ---------------------------------------------------------------------------
// GN apply + ReLU, in-place on a [N,64] bf16 buffer (2 channels per group)
// ---------------------------------------------------------------------------
__global__ void k_apply64(u16* __restrict__ buf, const float* __restrict__ st,
        const float* __restrict__ gamma, const float* __restrict__ beta, int n)
{
    const float cnt = (float)n * 2.0f;
    const int total = n * 8;
    for (int i = blockIdx.x * blockDim.x + threadIdx.x; i < total;
         i += gridDim.x * blockDim.x) {
        int c0 = (i & 7) * 8;
        short8 v = ((short8*)buf)[i];
#pragma unroll
        for (int j = 0; j < 8; ++j) {
            int c = c0 + j, g = c >> 1;
            float mu = st[g] / cnt;
            float var = st[32 + g] / cnt - mu * mu;
            float inv = rsqrtf(var + EPS);
            float x = bf2f(v[j]);
            x = fmaxf((x - mu) * inv * gamma[c] + beta[c], 0.f);
            v[j] = f2bf(x);
        }
        ((short8*)buf)[i] = v;
    }
}

// ---------------------------------------------------------------------------
// Octree conv (r9 structure, fastest measured): y[n,d] RAW = sum_k x@w3[k].
// 128 nodes x 64 d per block; chunked GLL staging of w3, 3 k-pages (24KB)
// per chunk, double-buffered (48KB LDS). Counted-vmcnt barriers; per step
// idx(k+4) -> gathers(k+2) -> compute(k). GN2 stats out.
// ---------------------------------------------------------------------------
__global__ __launch_bounds__(256) void k_conv(const u16* __restrict__ xb,
        const int* __restrict__ neigh, const u16* __restrict__ w3img,
        u16* __restrict__ y, float* __restrict__ stats, int n)
{
    __shared__ u16 s_w3[2][12288];    // 2 x 24KB (3 swizzled 8KB k-pages each)
    __shared__ float s_sum[32], s_sq[32];
    const int tid = threadIdx.x;
    if (tid < 32) { s_sum[tid] = 0.f; s_sq[tid] = 0.f; }
    const int row0 = blockIdx.x * 128;
    const int l = tid & 63, wv = tid >> 6;
    const int ll = l & 15, lh = l >> 4;
    const int r0 = row0 + wv * 32 + ll;
    const int r1 = r0 + 16;
    const int* __restrict__ nrow0 = neigh + (size_t)((r0 < n) ? r0 : 0) * KNB;
    const int* __restrict__ nrow1 = neigh + (size_t)((r1 < n) ? r1 : 0) * KNB;
    const int so = wv * 3072 + l * 8;   // ushort staging offset (6KB/wave)

    short8 A[3][4];     // gather register generations, slot k%3
    int ixa[3], ixb[3]; // idx generations, slot k%3

    // ---- prologue: idx(0,1) -> GLL(chunk0) -> gathers(0,1) -> idx(2,3) ----
    ixa[0] = nrow0[0]; ixb[0] = nrow1[0];
    ixa[1] = nrow0[1]; ixb[1] = nrow1[1];
    __builtin_amdgcn_sched_barrier(0);
#pragma unroll
    for (int j = 0; j < 6; ++j)
        GLL(w3img + so + j * 512, &s_w3[0][0] + so + j * 512);
    __builtin_amdgcn_sched_barrier(0);
    {
        const u16* xa = xb + (size_t)ixa[0] * CB + lh * 8;
        const u16* xc = xb + (size_t)ixb[0] * CB + lh * 8;
        A[0][0] = *(const short8*)xa; A[0][1] = *(const short8*)(xa + 32);
        A[0][2] = *(const short8*)xc; A[0][3] = *(const short8*)(xc + 32);
    }
    {
        const u16* xa = xb + (size_t)ixa[1] * CB + lh * 8;
        const u16* xc = xb + (size_t)ixb[1] * CB + lh * 8;
        A[1][0] = *(const short8*)xa; A[1][1] = *(const short8*)(xa + 32);
        A[1][2] = *(const short8*)xc; A[1][3] = *(const short8*)(xc + 32);
    }
    ixa[2] = nrow0[2]; ixb[2] = nrow1[2];
    ixa[0] = nrow0[3]; ixb[0] = nrow1[3];      // idx(3) -> slot 0 (idx0 dead)
    asm volatile("s_waitcnt vmcnt(12) lgkmcnt(0)" ::: "memory");
    __builtin_amdgcn_s_barrier();
    __builtin_amdgcn_sched_barrier(0);

    f32x4 acc[2][4] = {};
#pragma unroll
    for (int c = 0; c < 9; ++c) {
        const int buf = c & 1;
        if (c < 8) {   // stage chunk c+1 into other buffer (lands in ~3 steps)
            const u16* gsrc = w3img + (size_t)(c + 1) * 12288 + so;
            u16* ldst = &s_w3[buf ^ 1][0] + so;
#pragma unroll
            for (int j = 0; j < 6; ++j)
                GLL(gsrc + j * 512, ldst + j * 512);
        }
        __builtin_amdgcn_sched_barrier(0);
#pragma unroll
        for (int s = 0; s < 3; ++s) {
            const int k = c * 3 + s;
            if (k + 4 <= 26) {
                ixa[(k + 4) % 3] = nrow0[k + 4];
                ixb[(k + 4) % 3] = nrow1[k + 4];
            }
            __builtin_amdgcn_sched_barrier(0);
            if (k + 2 <= 26) {
                const u16* xa = xb + (size_t)ixa[(k + 2) % 3] * CB + lh * 8;
                const u16* xc = xb + (size_t)ixb[(k + 2) % 3] * CB + lh * 8;
                A[(k + 2) % 3][0] = *(const short8*)xa;
                A[(k + 2) % 3][1] = *(const short8*)(xa + 32);
                A[(k + 2) % 3][2] = *(const short8*)xc;
                A[(k + 2) % 3][3] = *(const short8*)(xc + 32);
            }
            __builtin_amdgcn_sched_barrier(0);
            const char* bpage = (const char*)&s_w3[buf][0] + s * 8192;
#pragma unroll
            for (int f = 0; f < 4; ++f) {
                int d = f * 16 + ll;
                int swz = (d & 7) << 4;
                short8 b0 = *(const short8*)(bpage + d * 128 + ((lh * 16) ^ swz));
                short8 b1 = *(const short8*)(bpage + d * 128 + ((64 + lh * 16) ^ swz));
                acc[0][f] = __builtin_amdgcn_mfma_f32_16x16x32_bf16(A[k % 3][0], b0, acc[0][f], 0, 0, 0);
                acc[0][f] = __builtin_amdgcn_mfma_f32_16x16x32_bf16(A[k % 3][1], b1, acc[0][f], 0, 0, 0);
                acc[1][f] = __builtin_amdgcn_mfma_f32_16x16x32_bf16(A[k % 3][2], b0, acc[1][f], 0, 0, 0);
                acc[1][f] = __builtin_amdgcn_mfma_f32_16x16x32_bf16(A[k % 3][3], b1, acc[1][f], 0, 0, 0);
            }
        }
        if (c < 7)
            asm volatile("s_waitcnt vmcnt(12) lgkmcnt(0)" ::: "memory");
        else if (c == 7)
            asm volatile("s_waitcnt vmcnt(10) lgkmcnt(0)" ::: "memory");
        if (c < 8) {
            __builtin_amdgcn_s_barrier();
            __builtin_amdgcn_sched_barrier(0);
        }
    }

    float gs[4] = {0.f, 0.f, 0.f, 0.f}, gq[4] = {0.f, 0.f, 0.f, 0.f};
#pragma unroll
    for (int rt = 0; rt < 2; ++rt) {
#pragma unroll
        for (int f = 0; f < 4; ++f) {
#pragma unroll
            for (int r = 0; r < 4; ++r) {
                int rr = row0 + wv * 32 + rt * 16 + lh * 4 + r;
                if (rr < n) {
                    float v = acc[rt][f][r];
                    y[(size_t)rr * CB + f * 16 + ll] = (u16)f2bf(v);
                    gs[f] += v; gq[f] += v * v;
                }
            }
        }
    }
#pragma unroll
    for (int f = 0; f < 4; ++f) {
        float s = gs[f], q = gq[f];
        s += __shfl_xor(s, 1); s += __shfl_xor(s, 16); s += __shfl_xor(s, 32);
        q += __shfl_xor(q, 1); q += __shfl_xor(q, 16); q += __shfl_xor(q, 32);
        if ((l & 0x31) == 0) {
            atomicAdd(&s_sum[f * 8 + (ll >> 1)], s);
            atomicAdd(&s_sq [f * 8 + (ll >> 1)], q);
        }
    }
    __syncthreads();
    if (tid < 32) {
        atomicAdd(&stats[64 + tid], s_sum[tid]);
        atomicAdd(&stats[96 + tid], s_sq[tid]);
    }
}

// ---------------------------------------------------------------------------
// GEMM2 (read-y-once): z[N,256] = relu(gn2(y)) @ w1b ; GN3 stats.
// 4 waves x 32 rows per block; 4 col-strips looped INSIDE the block so each
// y row is loaded exactly once. Stores bf16 zb (or f32 z fallback).
// ---------------------------------------------------------------------------
__global__ __launch_bounds__(256) void k_gemm2z(const u16* __restrict__ y2,
        const u16* __restrict__ w1bt, float* __restrict__ z, u16* __restrict__ zb,
        float* __restrict__ stats, const float* __restrict__ g3,
        const float* __restrict__ b3, int n)
{
    __shared__ float s_sum[32], s_sq[32];
    const int tid = threadIdx.x;
    if (tid < 32) { s_sum[tid] = 0.f; s_sq[tid] = 0.f; }
    __syncthreads();
    const int l = tid & 63, wv = tid >> 6;
    const int ll = l & 15, lh = l >> 4;
    const int rowbase = blockIdx.x * 128 + wv * 32;

    const float* st2 = stats + 64;
    const float cnt2 = (float)n * 2.0f;
    float sc[16], sh[16];
#pragma unroll
    for (int j = 0; j < 16; ++j) {
        int c = (j < 8) ? (lh * 8 + j) : (32 + lh * 8 + (j - 8));
        int g = c >> 1;
        float mu = st2[g] / cnt2;
        float var = st2[32 + g] / cnt2 - mu * mu;
        float inv = rsqrtf(var + EPS);
        float gm = g3[c];
        sc[j] = inv * gm;
        sh[j] = b3[c] - mu * inv * gm;
    }
    short8 A0[2], A1[2];
#pragma unroll
    for (int rt = 0; rt < 2; ++rt) {
        int row = rowbase + rt * 16 + ll;
        int rowc = (row < n) ? row : 0;
        const u16* ar = y2 + (size_t)rowc * CB + lh * 8;
        short8 r0 = *(const short8*)(ar);
        short8 r1 = *(const short8*)(ar + 32);
#pragma unroll
        for (int j = 0; j < 8; ++j) {
            A0[rt][j] = f2bf(fmaxf(bf2f(r0[j]) * sc[j] + sh[j], 0.f));
            A1[rt][j] = f2bf(fmaxf(bf2f(r1[j]) * sc[8 + j] + sh[8 + j], 0.f));
        }
    }
#pragma unroll
    for (int cb = 0; cb < 4; ++cb) {
        short8 b0[4], b1[4];
#pragma unroll
        for (int f = 0; f < 4; ++f) {
            const u16* br = w1bt + (size_t)(cb * 64 + f * 16 + ll) * CB + lh * 8;
            b0[f] = *(const short8*)(br);
            b1[f] = *(const short8*)(br + 32);
        }
        f32x4 acc[2][4] = {};
#pragma unroll
        for (int rt = 0; rt < 2; ++rt)
#pragma unroll
            for (int f = 0; f < 4; ++f) {
                acc[rt][f] = __builtin_amdgcn_mfma_f32_16x16x32_bf16(A0[rt], b0[f], acc[rt][f], 0, 0, 0);
                acc[rt][f] = __builtin_amdgcn_mfma_f32_16x16x32_bf16(A1[rt], b1[f], acc[rt][f], 0, 0, 0);
            }
#pragma unroll
        for (int f = 0; f < 4; ++f) {
            float gs = 0.f, gq = 0.f;
#pragma unroll
            for (int rt = 0; rt < 2; ++rt)
#pragma unroll
                for (int r = 0; r < 4; ++r) {
                    int rr = rowbase + rt * 16 + lh * 4 + r;
                    if (rr < n) {
                        float v = acc[rt][f][r];
                        size_t off = (size_t)rr * COUT + cb * 64 + f * 16 + ll;
                        if (zb) zb[off] = (u16)f2bf(v); else z[off] = v;
                        gs += v; gq += v * v;
                    }
                }
            gs += __shfl_xor(gs, 1); gs += __shfl_xor(gs, 2); gs += __shfl_xor(gs, 4);
            gs += __shfl_xor(gs, 16); gs += __shfl_xor(gs, 32);
            gq += __shfl_xor(gq, 1); gq += __shfl_xor(gq, 2); gq += __shfl_xor(gq, 4);
            gq += __shfl_xor(gq, 16); gq += __shfl_xor(gq, 32);
            if ((l & 0x37) == 0) {
                atomicAdd(&s_sum[cb * 8 + f * 2 + (ll >> 3)], gs);
                atomicAdd(&s_sq [cb * 8 + f * 2 + (ll >> 3)], gq);
            }
        }
    }
    __syncthreads();
    if (tid < 32) {
        atomicAdd(&stats[128 + tid], s_sum[tid]);
        atomicAdd(&stats[160 + tid], s_sq[tid]);
    }
}

// ---------------------------------------------------------------------------
// Final: out = relu(GN3(z) + data). bf16-z variant (z in ws).
// ---------------------------------------------------------------------------
__global__ void k_final_bf(float* __restrict__ out, const u16* __restrict__ zb,
        const float* __restrict__ data, const float* __restrict__ st,
        const float* __restrict__ gamma, const float* __restrict__ beta, int n)
{
    const float cnt = (float)n * 8.0f;
    const int total = n * 32;   // 8-channel chunks
    for (int i = blockIdx.x * blockDim.x + threadIdx.x; i < total;
         i += gridDim.x * blockDim.x) {
        int c0 = (i & 31) * 8;
        int g = c0 >> 3;
        float mu = st[g] / cnt;
        float var = st[32 + g] / cnt - mu * mu;
        float inv = rsqrtf(var + EPS);
        short8 zv = ((const short8*)zb)[i];
        float dd[8], oo[8];
        *(float4*)dd = *(const float4*)(data + (size_t)i * 8);
        *(float4*)(dd + 4) = *(const float4*)(data + (size_t)i * 8 + 4);
#pragma unroll
        for (int j = 0; j < 8; ++j)
            oo[j] = fmaxf((bf2f(zv[j]) - mu) * inv * gamma[c0 + j] + beta[c0 + j] + dd[j], 0.f);
        *(float4*)(out + (size_t)i * 8) = *(float4*)oo;
        *(float4*)(out + (size_t)i * 8 + 4) = *(float4*)(oo + 4);
    }
}

// f32-z fallback (z already in d_out), in-place
__global__ void k_final(float* __restrict__ zo, const float* __restrict__ data,
        const float* __restrict__ st, const float* __restrict__ gamma,
        const float* __restrict__ beta, int n)
{
    const float cnt = (float)n * 8.0f;
    const int total = n * (COUT / 4);
    for (int i = blockIdx.x * blockDim.x + threadIdx.x; i < total;
         i += gridDim.x * blockDim.x) {
        int c4 = (i & (COUT / 4 - 1)) * 4;
        int g = c4 >> 3;
        float mu = st[g] / cnt;
        float var = st[32 + g] / cnt - mu * mu;
        float inv = rsqrtf(var + EPS);
        float4 zv = *(float4*)(zo + (size_t)i * 4);
        float4 dv = *(const float4*)(data + (size_t)i * 4);
        zv.x = fmaxf((zv.x - mu) * inv * gamma[c4 + 0] + beta[c4 + 0] + dv.x, 0.f);
        zv.y = fmaxf((zv.y - mu) * inv * gamma[c4 + 1] + beta[c4 + 1] + dv.y, 0.f);
        zv.z = fmaxf((zv.z - mu) * inv * gamma[c4 + 2] + beta[c4 + 2] + dv.z, 0.f);
        zv.w = fmaxf((zv.w - mu) * inv * gamma[c4 + 3] + beta[c4 + 3] + dv.w, 0.f);
        *(float4*)(zo + (size_t)i * 4) = zv;
    }
}

// ---------------------------------------------------------------------------
extern "C" void kernel_launch(void* const* d_in, const int* in_sizes, int n_in,
                              void* d_out, int out_size, void* d_ws, size_t ws_size,
                              hipStream_t stream)
{
    const float* data = (const float*)d_in[0];
    const int*   neigh = (const int*)d_in[1];
    const float* w1a = (const float*)d_in[2];
    const float* g1a = (const float*)d_in[3];
    const float* b1a = (const float*)d_in[4];
    const float* w3  = (const float*)d_in[5];
    const float* g3  = (const float*)d_in[6];
    const float* b3  = (const float*)d_in[7];
    const float* w1b = (const float*)d_in[8];
    const float* g1b = (const float*)d_in[9];
    const float* b1b = (const float*)d_in[10];
    float* out = (float*)d_out;
    float* ws  = (float*)d_ws;

    const int n = in_sizes[0] / CIN;   // 150000

    // ws layout: stats[192] (pad 256 f32) | w1at | w3img | w1bt | t1 | ybuf | [zb]
    float* stats = ws;
    u16* w1at  = (u16*)(ws + 256);
    u16* w3img = w1at + 16384;
    u16* w1bt  = w3img + 110592;
    u16* t1    = w1bt + 16384;
    u16* ybuf  = t1 + (size_t)n * CB;
    u16* zb    = nullptr;
    {
        size_t need = 1024 + 286720 + (size_t)n * CB * 4 + (size_t)n * COUT * 2;
        if (ws_size >= need) zb = ybuf + (size_t)n * CB;
    }

    hipMemsetAsync(stats, 0, 192 * sizeof(float), stream);

    const int nb128 = (n + 127) / 128;
    const int nb256 = (n + 255) / 256;
    k_prep<<<560, 256, 0, stream>>>(w1a, w3, w1b, w1at, w3img, w1bt);
    k_gemm1<<<nb256, 256, 0, stream>>>(data, w1at, t1, stats, n);
    k_apply64<<<2048, 256, 0, stream>>>(t1, stats, g1a, b1a, n);
    k_conv<<<nb128, 256, 0, stream>>>(t1, neigh, w3img, ybuf, stats, n);
    k_gemm2z<<<nb128, 256, 0, stream>>>(ybuf, w1bt, out, zb, stats, g3, b3, n);
    if (zb)
        k_final_bf<<<2048, 256, 0, stream>>>(out, zb, data, stats + 128, g1b, b1b, n);
    else
        k_final<<<2048, 256, 0, stream>>>(out, data, stats + 128, g1b, b1b, n);
}

// Round 16
// 282.895 us; speedup vs baseline: 1.0372x; 1.0372x over previous
//
#include <hip/hip_runtime.h>
#include <math.h>

#define CIN 256
#define CB 64
#define COUT 256
#define KNB 27
#define EPS 1e-5f

typedef unsigned short u16;
typedef __attribute__((ext_vector_type(8))) short short8;
typedef __attribute__((ext_vector_type(4))) float f32x4;

typedef const __attribute__((address_space(1))) unsigned int* gas_u32p;
typedef __attribute__((address_space(3))) unsigned int* las_u32p;
#define GLL(g, p) __builtin_amdgcn_global_load_lds((gas_u32p)(const void*)(g), \
        (las_u32p)(void*)(p), 16, 0, 0)

__device__ inline short f2bf(float f) {
    union { float f; unsigned u; } v; v.f = f;
    unsigned r = v.u + 0x7fff + ((v.u >> 16) & 1);   // RNE
    return (short)(r >> 16);
}
__device__ inline float bf2f(short s) {
    union { unsigned u; float f; } v; v.u = ((unsigned)(u16)s) << 16;
    return v.f;
}
__device__ inline short8 pack8(float4 x0, float4 x1) {
    short8 r;
    r[0] = f2bf(x0.x); r[1] = f2bf(x0.y); r[2] = f2bf(x0.z); r[3] = f2bf(x0.w);
    r[4] = f2bf(x1.x); r[5] = f2bf(x1.y); r[6] = f2bf(x1.z); r[7] = f2bf(x1.w);
    return r;
}

// ---------------------------------------------------------------------------
// Weight prep: bf16 conversion + transposes (+ XOR-swizzled w3 LDS image)
// ---------------------------------------------------------------------------
__global__ void k_prep(const float* __restrict__ w1a, const float* __restrict__ w3,
                       const float* __restrict__ w1b, u16* __restrict__ w1at,
                       u16* __restrict__ w3img, u16* __restrict__ w1bt)
{
    int i = blockIdx.x * 256 + threadIdx.x;
    if (i < 16384) {
        int k = i >> 6, d = i & 63;
        w1at[d * 256 + k] = (u16)f2bf(w1a[i]);
    } else if (i < 126976) {
        int j = i - 16384;
        int k = j >> 12, c = (j >> 6) & 63, d = j & 63;
        w3img[(size_t)k * 4096 + d * 64 + (c ^ ((d & 7) << 3))] = (u16)f2bf(w3[j]);
    } else if (i < 143360) {
        int j = i - 126976;
        int c = j >> 8, d = j & 255;
        w1bt[d * 64 + c] = (u16)f2bf(w1b[j]);
    }
}

// ---------------------------------------------------------------------------
// GEMM1: t1[N,64](bf16, RAW) = data[N,256](f32->bf16) @ w1a ; GN1 stats
// ---------------------------------------------------------------------------
__global__ __launch_bounds__(256) void k_gemm1(const float* __restrict__ data,
        const u16* __restrict__ w1at, u16* __restrict__ t1,
        float* __restrict__ stats, int n)
{
    __shared__ float s_sum[32], s_sq[32];
    const int tid = threadIdx.x;
    if (tid < 32) { s_sum[tid] = 0.f; s_sq[tid] = 0.f; }
    __syncthreads();
    const int l = tid & 63, wv = tid >> 6;
    const int ll = l & 15, lh = l >> 4;
    const int rowbase = blockIdx.x * 256 + wv * 64;

    f32x4 acc[4][4] = {};
#pragma unroll
    for (int kc = 0; kc < 8; ++kc) {
        short8 b[4];
#pragma unroll
        for (int f = 0; f < 4; ++f)
            b[f] = *(const short8*)(w1at + (size_t)(f * 16 + ll) * 256 + kc * 32 + lh * 8);
#pragma unroll
        for (int rt = 0; rt < 4; ++rt) {
            int row = rowbase + rt * 16 + ll;
            int rowc = (row < n) ? row : 0;
            const float* ar = data + (size_t)rowc * CIN + kc * 32 + lh * 8;
            short8 a = pack8(*(const float4*)ar, *(const float4*)(ar + 4));
#pragma unroll
            for (int f = 0; f < 4; ++f)
                acc[rt][f] = __builtin_amdgcn_mfma_f32_16x16x32_bf16(a, b[f], acc[rt][f], 0, 0, 0);
        }
    }
    float gs[4] = {0.f, 0.f, 0.f, 0.f}, gq[4] = {0.f, 0.f, 0.f, 0.f};
#pragma unroll
    for (int rt = 0; rt < 4; ++rt) {
#pragma unroll
        for (int f = 0; f < 4; ++f) {
#pragma unroll
            for (int r = 0; r < 4; ++r) {
                int rr = rowbase + rt * 16 + lh * 4 + r;
                if (rr < n) {
                    float v = acc[rt][f][r];
                    t1[(size_t)rr * CB + f * 16 + ll] = (u16)f2bf(v);
                    gs[f] += v; gq[f] += v * v;
                }
            }
        }
    }
#pragma unroll
    for (int f = 0; f < 4; ++f) {
        float s = gs[f], q = gq[f];
        s += __shfl_xor(s, 1); s += __shfl_xor(s, 16); s += __shfl_xor(s, 32);
        q += __shfl_xor(q, 1); q += __shfl_xor(q, 16); q += __shfl_xor(q, 32);
        if ((l & 0x31) == 0) {
            atomicAdd(&s_sum[f * 8 + (ll >> 1)], s);
            atomicAdd(&s_sq [f * 8 + (ll >> 1)], q);
        }
    }
    __syncthreads();
    if (tid < 32) {
        atomicAdd(&stats[tid], s_sum[tid]);
        atomicAdd(&stats[32 + tid], s_sq[tid]);
    }
}

// ---------------------------------------------------------------------------
// GN apply + ReLU, in-place on a [N,64] bf16 buffer (2 channels per group)
// ---------------------------------------------------------------------------
__global__ void k_apply64(u16* __restrict__ buf, const float* __restrict__ st,
        const float* __restrict__ gamma, const float* __restrict__ beta, int n)
{
    const float cnt = (float)n * 2.0f;
    const int total = n * 8;
    for (int i = blockIdx.x * blockDim.x + threadIdx.x; i < total;
         i += gridDim.x * blockDim.x) {
        int c0 = (i & 7) * 8;
        short8 v = ((short8*)buf)[i];
#pragma unroll
        for (int j = 0; j < 8; ++j) {
            int c = c0 + j, g = c >> 1;
            float mu = st[g] / cnt;
            float var = st[32 + g] / cnt - mu * mu;
            float inv = rsqrtf(var + EPS);
            float x = bf2f(v[j]);
            x = fmaxf((x - mu) * inv * gamma[c] + beta[c], 0.f);
            v[j] = f2bf(x);
        }
        ((short8*)buf)[i] = v;
    }
}

// ---------------------------------------------------------------------------
// Octree conv (r9 structure, fastest measured): y[n,d] RAW = sum_k x@w3[k].
// 128 nodes x 64 d per block; chunked GLL staging of w3, 3 k-pages (24KB)
// per chunk, double-buffered (48KB LDS). Counted-vmcnt barriers; per step
// idx(k+4) -> gathers(k+2) -> compute(k). GN2 stats out.
// ---------------------------------------------------------------------------
__global__ __launch_bounds__(256) void k_conv(const u16* __restrict__ xb,
        const int* __restrict__ neigh, const u16* __restrict__ w3img,
        u16* __restrict__ y, float* __restrict__ stats, int n)
{
    __shared__ u16 s_w3[2][12288];    // 2 x 24KB (3 swizzled 8KB k-pages each)
    __shared__ float s_sum[32], s_sq[32];
    const int tid = threadIdx.x;
    if (tid < 32) { s_sum[tid] = 0.f; s_sq[tid] = 0.f; }
    const int row0 = blockIdx.x * 128;
    const int l = tid & 63, wv = tid >> 6;
    const int ll = l & 15, lh = l >> 4;
    const int r0 = row0 + wv * 32 + ll;
    const int r1 = r0 + 16;
    const int* __restrict__ nrow0 = neigh + (size_t)((r0 < n) ? r0 : 0) * KNB;
    const int* __restrict__ nrow1 = neigh + (size_t)((r1 < n) ? r1 : 0) * KNB;
    const int so = wv * 3072 + l * 8;   // ushort staging offset (6KB/wave)

    short8 A[3][4];     // gather register generations, slot k%3
    int ixa[3], ixb[3]; // idx generations, slot k%3

    // ---- prologue: idx(0,1) -> GLL(chunk0) -> gathers(0,1) -> idx(2,3) ----
    ixa[0] = nrow0[0]; ixb[0] = nrow1[0];
    ixa[1] = nrow0[1]; ixb[1] = nrow1[1];
    __builtin_amdgcn_sched_barrier(0);
#pragma unroll
    for (int j = 0; j < 6; ++j)
        GLL(w3img + so + j * 512, &s_w3[0][0] + so + j * 512);
    __builtin_amdgcn_sched_barrier(0);
    {
        const u16* xa = xb + (size_t)ixa[0] * CB + lh * 8;
        const u16* xc = xb + (size_t)ixb[0] * CB + lh * 8;
        A[0][0] = *(const short8*)xa; A[0][1] = *(const short8*)(xa + 32);
        A[0][2] = *(const short8*)xc; A[0][3] = *(const short8*)(xc + 32);
    }
    {
        const u16* xa = xb + (size_t)ixa[1] * CB + lh * 8;
        const u16* xc = xb + (size_t)ixb[1] * CB + lh * 8;
        A[1][0] = *(const short8*)xa; A[1][1] = *(const short8*)(xa + 32);
        A[1][2] = *(const short8*)xc; A[1][3] = *(const short8*)(xc + 32);
    }
    ixa[2] = nrow0[2]; ixb[2] = nrow1[2];
    ixa[0] = nrow0[3]; ixb[0] = nrow1[3];      // idx(3) -> slot 0 (idx0 dead)
    asm volatile("s_waitcnt vmcnt(12) lgkmcnt(0)" ::: "memory");
    __builtin_amdgcn_s_barrier();
    __builtin_amdgcn_sched_barrier(0);

    f32x4 acc[2][4] = {};
#pragma unroll
    for (int c = 0; c < 9; ++c) {
        const int buf = c & 1;
        if (c < 8) {   // stage chunk c+1 into other buffer (lands in ~3 steps)
            const u16* gsrc = w3img + (size_t)(c + 1) * 12288 + so;
            u16* ldst = &s_w3[buf ^ 1][0] + so;
#pragma unroll
            for (int j = 0; j < 6; ++j)
                GLL(gsrc + j * 512, ldst + j * 512);
        }
        __builtin_amdgcn_sched_barrier(0);
#pragma unroll
        for (int s = 0; s < 3; ++s) {
            const int k = c * 3 + s;
            if (k + 4 <= 26) {
                ixa[(k + 4) % 3] = nrow0[k + 4];
                ixb[(k + 4) % 3] = nrow1[k + 4];
            }
            __builtin_amdgcn_sched_barrier(0);
            if (k + 2 <= 26) {
                const u16* xa = xb + (size_t)ixa[(k + 2) % 3] * CB + lh * 8;
                const u16* xc = xb + (size_t)ixb[(k + 2) % 3] * CB + lh * 8;
                A[(k + 2) % 3][0] = *(const short8*)xa;
                A[(k + 2) % 3][1] = *(const short8*)(xa + 32);
                A[(k + 2) % 3][2] = *(const short8*)xc;
                A[(k + 2) % 3][3] = *(const short8*)(xc + 32);
            }
            __builtin_amdgcn_sched_barrier(0);
            const char* bpage = (const char*)&s_w3[buf][0] + s * 8192;
#pragma unroll
            for (int f = 0; f < 4; ++f) {
                int d = f * 16 + ll;
                int swz = (d & 7) << 4;
                short8 b0 = *(const short8*)(bpage + d * 128 + ((lh * 16) ^ swz));
                short8 b1 = *(const short8*)(bpage + d * 128 + ((64 + lh * 16) ^ swz));
                acc[0][f] = __builtin_amdgcn_mfma_f32_16x16x32_bf16(A[k % 3][0], b0, acc[0][f], 0, 0, 0);
                acc[0][f] = __builtin_amdgcn_mfma_f32_16x16x32_bf16(A[k % 3][1], b1, acc[0][f], 0, 0, 0);
                acc[1][f] = __builtin_amdgcn_mfma_f32_16x16x32_bf16(A[k % 3][2], b0, acc[1][f], 0, 0, 0);
                acc[1][f] = __builtin_amdgcn_mfma_f32_16x16x32_bf16(A[k % 3][3], b1, acc[1][f], 0, 0, 0);
            }
        }
        if (c < 7)
            asm volatile("s_waitcnt vmcnt(12) lgkmcnt(0)" ::: "memory");
        else if (c == 7)
            asm volatile("s_waitcnt vmcnt(10) lgkmcnt(0)" ::: "memory");
        if (c < 8) {
            __builtin_amdgcn_s_barrier();
            __builtin_amdgcn_sched_barrier(0);
        }
    }

    float gs[4] = {0.f, 0.f, 0.f, 0.f}, gq[4] = {0.f, 0.f, 0.f, 0.f};
#pragma unroll
    for (int rt = 0; rt < 2; ++rt) {
#pragma unroll
        for (int f = 0; f < 4; ++f) {
#pragma unroll
            for (int r = 0; r < 4; ++r) {
                int rr = row0 + wv * 32 + rt * 16 + lh * 4 + r;
                if (rr < n) {
                    float v = acc[rt][f][r];
                    y[(size_t)rr * CB + f * 16 + ll] = (u16)f2bf(v);
                    gs[f] += v; gq[f] += v * v;
                }
            }
        }
    }
#pragma unroll
    for (int f = 0; f < 4; ++f) {
        float s = gs[f], q = gq[f];
        s += __shfl_xor(s, 1); s += __shfl_xor(s, 16); s += __shfl_xor(s, 32);
        q += __shfl_xor(q, 1); q += __shfl_xor(q, 16); q += __shfl_xor(q, 32);
        if ((l & 0x31) == 0) {
            atomicAdd(&s_sum[f * 8 + (ll >> 1)], s);
            atomicAdd(&s_sq [f * 8 + (ll >> 1)], q);
        }
    }
    __syncthreads();
    if (tid < 32) {
        atomicAdd(&stats[64 + tid], s_sum[tid]);
        atomicAdd(&stats[96 + tid], s_sq[tid]);
    }
}

// ---------------------------------------------------------------------------
// GEMM2 with fused GN2-apply on the A path (r9 grid: (nb256, 4)):
// z[N,256] = relu(gn2(y))[N,64](bf16) @ w1b ; GN3 stats.
// Stores bf16 into zb (if non-null) else f32 into z.
// ---------------------------------------------------------------------------
__global__ __launch_bounds__(256) void k_gemm2(const u16* __restrict__ y2,
        const u16* __restrict__ w1bt, float* __restrict__ z, u16* __restrict__ zb,
        float* __restrict__ stats, const float* __restrict__ g3,
        const float* __restrict__ b3, int n)
{
    __shared__ float s_sum[8], s_sq[8];
    const int tid = threadIdx.x;
    if (tid < 8) { s_sum[tid] = 0.f; s_sq[tid] = 0.f; }
    __syncthreads();
    const int l = tid & 63, wv = tid >> 6;
    const int ll = l & 15, lh = l >> 4;
    const int rowbase = blockIdx.x * 256 + wv * 64;
    const int cb = blockIdx.y;

    const float* st2 = stats + 64;
    const float cnt2 = (float)n * 2.0f;
    float sc[16], sh[16];
#pragma unroll
    for (int j = 0; j < 16; ++j) {
        int c = (j < 8) ? (lh * 8 + j) : (32 + lh * 8 + (j - 8));
        int g = c >> 1;
        float mu = st2[g] / cnt2;
        float var = st2[32 + g] / cnt2 - mu * mu;
        float inv = rsqrtf(var + EPS);
        float gm = g3[c];
        sc[j] = inv * gm;
        sh[j] = b3[c] - mu * inv * gm;
    }

    short8 b0[4], b1[4];
#pragma unroll
    for (int f = 0; f < 4; ++f) {
        const u16* br = w1bt + (size_t)(cb * 64 + f * 16 + ll) * CB + lh * 8;
        b0[f] = *(const short8*)(br);
        b1[f] = *(const short8*)(br + 32);
    }
    f32x4 acc[4][4] = {};
#pragma unroll
    for (int rt = 0; rt < 4; ++rt) {
        int row = rowbase + rt * 16 + ll;
        int rowc = (row < n) ? row : 0;
        const u16* ar = y2 + (size_t)rowc * CB + lh * 8;
        short8 r0 = *(const short8*)(ar);
        short8 r1 = *(const short8*)(ar + 32);
        short8 a0, a1;
#pragma unroll
        for (int j = 0; j < 8; ++j) {
            a0[j] = f2bf(fmaxf(bf2f(r0[j]) * sc[j] + sh[j], 0.f));
            a1[j] = f2bf(fmaxf(bf2f(r1[j]) * sc[8 + j] + sh[8 + j], 0.f));
        }
#pragma unroll
        for (int f = 0; f < 4; ++f) {
            acc[rt][f] = __builtin_amdgcn_mfma_f32_16x16x32_bf16(a0, b0[f], acc[rt][f], 0, 0, 0);
            acc[rt][f] = __builtin_amdgcn_mfma_f32_16x16x32_bf16(a1, b1[f], acc[rt][f], 0, 0, 0);
        }
    }
    float gs[4] = {0.f, 0.f, 0.f, 0.f}, gq[4] = {0.f, 0.f, 0.f, 0.f};
#pragma unroll
    for (int rt = 0; rt < 4; ++rt) {
#pragma unroll
        for (int f = 0; f < 4; ++f) {
#pragma unroll
            for (int r = 0; r < 4; ++r) {
                int rr = rowbase + rt * 16 + lh * 4 + r;
                if (rr < n) {
                    float v = acc[rt][f][r];
                    size_t off = (size_t)rr * COUT + cb * 64 + f * 16 + ll;
                    if (zb) zb[off] = (u16)f2bf(v); else z[off] = v;
                    gs[f] += v; gq[f] += v * v;
                }
            }
        }
    }
#pragma unroll
    for (int f = 0; f < 4; ++f) {
        float s = gs[f], q = gq[f];
        s += __shfl_xor(s, 1); s += __shfl_xor(s, 2); s += __shfl_xor(s, 4);
        s += __shfl_xor(s, 16); s += __shfl_xor(s, 32);
        q += __shfl_xor(q, 1); q += __shfl_xor(q, 2); q += __shfl_xor(q, 4);
        q += __shfl_xor(q, 16); q += __shfl_xor(q, 32);
        if ((l & 0x37) == 0) {
            atomicAdd(&s_sum[f * 2 + (ll >> 3)], s);
            atomicAdd(&s_sq [f * 2 + (ll >> 3)], q);
        }
    }
    __syncthreads();
    if (tid < 8) {
        atomicAdd(&stats[128 + cb * 8 + tid], s_sum[tid]);
        atomicAdd(&stats[160 + cb * 8 + tid], s_sq[tid]);
    }
}

// ---------------------------------------------------------------------------
// Final: out = relu(GN3(z) + data). bf16-z variant (z in ws).
// ---------------------------------------------------------------------------
__global__ void k_final_bf(float* __restrict__ out, const u16* __restrict__ zb,
        const float* __restrict__ data, const float* __restrict__ st,
        const float* __restrict__ gamma, const float* __restrict__ beta, int n)
{
    const float cnt = (float)n * 8.0f;
    const int total = n * 32;   // 8-channel chunks
    for (int i = blockIdx.x * blockDim.x + threadIdx.x; i < total;
         i += gridDim.x * blockDim.x) {
        int c0 = (i & 31) * 8;
        int g = c0 >> 3;
        float mu = st[g] / cnt;
        float var = st[32 + g] / cnt - mu * mu;
        float inv = rsqrtf(var + EPS);
        short8 zv = ((const short8*)zb)[i];
        float dd[8], oo[8];
        *(float4*)dd = *(const float4*)(data + (size_t)i * 8);
        *(float4*)(dd + 4) = *(const float4*)(data + (size_t)i * 8 + 4);
#pragma unroll
        for (int j = 0; j < 8; ++j)
            oo[j] = fmaxf((bf2f(zv[j]) - mu) * inv * gamma[c0 + j] + beta[c0 + j] + dd[j], 0.f);
        *(float4*)(out + (size_t)i * 8) = *(float4*)oo;
        *(float4*)(out + (size_t)i * 8 + 4) = *(float4*)(oo + 4);
    }
}

// f32-z fallback (z already in d_out), in-place
__global__ void k_final(float* __restrict__ zo, const float* __restrict__ data,
        const float* __restrict__ st, const float* __restrict__ gamma,
        const float* __restrict__ beta, int n)
{
    const float cnt = (float)n * 8.0f;
    const int total = n * (COUT / 4);
    for (int i = blockIdx.x * blockDim.x + threadIdx.x; i < total;
         i += gridDim.x * blockDim.x) {
        int c4 = (i & (COUT / 4 - 1)) * 4;
        int g = c4 >> 3;
        float mu = st[g] / cnt;
        float var = st[32 + g] / cnt - mu * mu;
        float inv = rsqrtf(var + EPS);
        float4 zv = *(float4*)(zo + (size_t)i * 4);
        float4 dv = *(const float4*)(data + (size_t)i * 4);
        zv.x = fmaxf((zv.x - mu) * inv * gamma[c4 + 0] + beta[c4 + 0] + dv.x, 0.f);
        zv.y = fmaxf((zv.y - mu) * inv * gamma[c4 + 1] + beta[c4 + 1] + dv.y, 0.f);
        zv.z = fmaxf((zv.z - mu) * inv * gamma[c4 + 2] + beta[c4 + 2] + dv.z, 0.f);
        zv.w = fmaxf((zv.w - mu) * inv * gamma[c4 + 3] + beta[c4 + 3] + dv.w, 0.f);
        *(float4*)(zo + (size_t)i * 4) = zv;
    }
}

// ---------------------------------------------------------------------------
extern "C" void kernel_launch(void* const* d_in, const int* in_sizes, int n_in,
                              void* d_out, int out_size, void* d_ws, size_t ws_size,
                              hipStream_t stream)
{
    const float* data = (const float*)d_in[0];
    const int*   neigh = (const int*)d_in[1];
    const float* w1a = (const float*)d_in[2];
    const float* g1a = (const float*)d_in[3];
    const float* b1a = (const float*)d_in[4];
    const float* w3  = (const float*)d_in[5];
    const float* g3  = (const float*)d_in[6];
    const float* b3  = (const float*)d_in[7];
    const float* w1b = (const float*)d_in[8];
    const float* g1b = (const float*)d_in[9];
    const float* b1b = (const float*)d_in[10];
    float* out = (float*)d_out;
    float* ws  = (float*)d_ws;

    const int n = in_sizes[0] / CIN;   // 150000

    // ws layout: stats[192] (pad 256 f32) | w1at | w3img | w1bt | t1 | ybuf | [zb]
    float* stats = ws;
    u16* w1at  = (u16*)(ws + 256);
    u16* w3img = w1at + 16384;
    u16* w1bt  = w3img + 110592;
    u16* t1    = w1bt + 16384;
    u16* ybuf  = t1 + (size_t)n * CB;
    u16* zb    = nullptr;
    {
        size_t need = 1024 + 286720 + (size_t)n * CB * 4 + (size_t)n * COUT * 2;
        if (ws_size >= need) zb = ybuf + (size_t)n * CB;
    }

    hipMemsetAsync(stats, 0, 192 * sizeof(float), stream);

    const int nb128 = (n + 127) / 128;
    const int nb256 = (n + 255) / 256;
    k_prep<<<560, 256, 0, stream>>>(w1a, w3, w1b, w1at, w3img, w1bt);
    k_gemm1<<<nb256, 256, 0, stream>>>(data, w1at, t1, stats, n);
    k_apply64<<<2048, 256, 0, stream>>>(t1, stats, g1a, b1a, n);
    k_conv<<<nb128, 256, 0, stream>>>(t1, neigh, w3img, ybuf, stats, n);
    k_gemm2<<<dim3(nb256, 4), 256, 0, stream>>>(ybuf, w1bt, out, zb, stats, g3, b3, n);
    if (zb)
        k_final_bf<<<2048, 256, 0, stream>>>(out, zb, data, stats + 128, g1b, b1b, n);
    else
        k_final<<<2048, 256, 0, stream>>>(out, data, stats + 128, g1b, b1b, n);
}